// Round 1
// baseline (2988.399 us; speedup 1.0000x reference)
//
#include <hip/hip_runtime.h>
#include <hip/hip_bf16.h>
#include <math.h>

#define N_NODES_C 100000
#define N_EDGES_C 1600000
#define N_GRAPHS_C 512

__device__ __forceinline__ float elu_f(float x) { return x > 0.f ? x : expm1f(x); }

// ---------------------------------------------------------------------------
// Scatter-add: agg[dst] += x[src], edge-parallel, float4 per thread.
// D = feature dim (32 or 64). 8 or 16 consecutive threads handle one edge,
// so the gather of a 128/256B row is coalesced. Atomics via hardware
// global_atomic_add_f32 (unsafeAtomicAdd).
// ---------------------------------------------------------------------------
template<int D>
__global__ __launch_bounds__(256) void scatter_kernel(
    const float* __restrict__ x, const int* __restrict__ src,
    const int* __restrict__ dst, float* __restrict__ agg, int nEdges)
{
    const int VPE = D / 4;  // float4 chunks per edge
    long long idx = (long long)blockIdx.x * 256 + threadIdx.x;
    long long total = (long long)nEdges * VPE;
    if (idx >= total) return;
    int e = (int)(idx / VPE);
    int c = (int)(idx % VPE);
    int s = src[e];
    int d = dst[e];
    float4 v = *reinterpret_cast<const float4*>(x + (size_t)s * D + c * 4);
    float* p = agg + (size_t)d * D + c * 4;
    unsafeAtomicAdd(p + 0, v.x);
    unsafeAtomicAdd(p + 1, v.y);
    unsafeAtomicAdd(p + 2, v.z);
    unsafeAtomicAdd(p + 3, v.w);
}

// ---------------------------------------------------------------------------
// Node transform: out[n][j] = ELU( sum_k agg[n][k]*w_rel[k][j]
//                                + sum_k x[n][k]*w_root[k][j] + b[j] )
// Weights staged in LDS. Thread = (node-in-block, out feature j).
// ---------------------------------------------------------------------------
template<int DIN, int DOUT>
__global__ __launch_bounds__(256) void transform_kernel(
    const float* __restrict__ agg, const float* __restrict__ xin,
    const float* __restrict__ w_rel, const float* __restrict__ bias,
    const float* __restrict__ w_root, float* __restrict__ out, int nNodes)
{
    __shared__ float wr[DIN * DOUT];
    __shared__ float wt[DIN * DOUT];
    for (int i = threadIdx.x; i < DIN * DOUT; i += 256) {
        wr[i] = w_rel[i];
        wt[i] = w_root[i];
    }
    __syncthreads();

    const int NPB = 256 / DOUT;  // nodes per block
    int local = threadIdx.x / DOUT;
    int j = threadIdx.x % DOUT;
    int n = blockIdx.x * NPB + local;
    if (n >= nNodes) return;

    const float* ar = agg + (size_t)n * DIN;
    const float* xr = xin + (size_t)n * DIN;
    float acc = bias[j];
#pragma unroll
    for (int k = 0; k < DIN; ++k) {
        acc += ar[k] * wr[k * DOUT + j] + xr[k] * wt[k * DOUT + j];
    }
    out[(size_t)n * DOUT + j] = elu_f(acc);
}

// ---------------------------------------------------------------------------
// Mean-pool over sorted `batch`: each 64-thread block walks a chunk of nodes,
// thread j owns feature j, flushing one atomic per graph-boundary crossed.
// ---------------------------------------------------------------------------
#define POOL_CHUNK 256
__global__ __launch_bounds__(64) void pool_kernel(
    const float* __restrict__ h, const int* __restrict__ batch,
    float* __restrict__ sums, float* __restrict__ cnts, int nNodes)
{
    int j = threadIdx.x;  // 0..63
    int start = blockIdx.x * POOL_CHUNK;
    int end = start + POOL_CHUNK;
    if (end > nNodes) end = nNodes;
    if (start >= end) return;

    int g = batch[start];
    float acc = 0.f;
    float c = 0.f;
    for (int n = start; n < end; ++n) {
        int gn = batch[n];
        if (gn != g) {
            unsafeAtomicAdd(&sums[(size_t)g * 64 + j], acc);
            if (j == 0) unsafeAtomicAdd(&cnts[g], c);
            acc = 0.f; c = 0.f; g = gn;
        }
        acc += h[(size_t)n * 64 + j];
        c += 1.f;
    }
    unsafeAtomicAdd(&sums[(size_t)g * 64 + j], acc);
    if (j == 0) unsafeAtomicAdd(&cnts[g], c);
}

// ---------------------------------------------------------------------------
// MLP head + log_softmax: one 64-thread block per graph, all in LDS.
// z1 = elu(p@fw1+fb1) [64]; z2 = elu(z1@fw2+fb2) [32]; z3 = z2@fw3+fb3 [10]
// ---------------------------------------------------------------------------
__global__ __launch_bounds__(64) void mlp_kernel(
    const float* __restrict__ sums, const float* __restrict__ cnts,
    const float* __restrict__ fw1, const float* __restrict__ fb1,
    const float* __restrict__ fw2, const float* __restrict__ fb2,
    const float* __restrict__ fw3, const float* __restrict__ fb3,
    float* __restrict__ out)
{
    int g = blockIdx.x;
    int j = threadIdx.x;  // 0..63
    __shared__ float p[64];
    __shared__ float z1[64];
    __shared__ float z2[32];
    __shared__ float z3[10];
    __shared__ float lse;

    float c = fmaxf(cnts[g], 1.f);
    p[j] = sums[(size_t)g * 64 + j] / c;
    __syncthreads();

    float a = fb1[j];
#pragma unroll
    for (int k = 0; k < 64; ++k) a += p[k] * fw1[k * 64 + j];
    z1[j] = elu_f(a);
    __syncthreads();

    if (j < 32) {
        float a2 = fb2[j];
#pragma unroll
        for (int k = 0; k < 64; ++k) a2 += z1[k] * fw2[k * 32 + j];
        z2[j] = elu_f(a2);
    }
    __syncthreads();

    if (j < 10) {
        float a3 = fb3[j];
#pragma unroll
        for (int k = 0; k < 32; ++k) a3 += z2[k] * fw3[k * 10 + j];
        z3[j] = a3;
    }
    __syncthreads();

    if (j == 0) {
        float m = -1e30f;
        for (int i = 0; i < 10; ++i) m = fmaxf(m, z3[i]);
        float s = 0.f;
        for (int i = 0; i < 10; ++i) s += expf(z3[i] - m);
        lse = logf(s) + m;
    }
    __syncthreads();

    if (j < 10) out[(size_t)g * 10 + j] = z3[j] - lse;
}

// ---------------------------------------------------------------------------
extern "C" void kernel_launch(void* const* d_in, const int* in_sizes, int n_in,
                              void* d_out, int out_size, void* d_ws, size_t ws_size,
                              hipStream_t stream)
{
    const float* x       = (const float*)d_in[0];
    const int*   ei      = (const int*)  d_in[1];
    const int*   batch   = (const int*)  d_in[2];
    const float* w1_rel  = (const float*)d_in[3];
    const float* b1      = (const float*)d_in[4];
    const float* w1_root = (const float*)d_in[5];
    const float* w2_rel  = (const float*)d_in[6];
    const float* b2      = (const float*)d_in[7];
    const float* w2_root = (const float*)d_in[8];
    const float* w3_rel  = (const float*)d_in[9];
    const float* b3      = (const float*)d_in[10];
    const float* w3_root = (const float*)d_in[11];
    const float* fw1     = (const float*)d_in[12];
    const float* fb1     = (const float*)d_in[13];
    const float* fw2     = (const float*)d_in[14];
    const float* fb2     = (const float*)d_in[15];
    const float* fw3     = (const float*)d_in[16];
    const float* fb3     = (const float*)d_in[17];
    float* out = (float*)d_out;

    const int* src = ei;
    const int* dst = ei + N_EDGES_C;

    // workspace layout (floats)
    float* agg  = (float*)d_ws;                         // N*64
    float* hB   = agg  + (size_t)N_NODES_C * 64;        // N*64
    float* hC   = hB   + (size_t)N_NODES_C * 64;        // N*64
    float* sums = hC   + (size_t)N_NODES_C * 64;        // 512*64
    float* cnts = sums + (size_t)N_GRAPHS_C * 64;       // 512

    // ---- layer 1: d_in=32 -> d_out=32, input x, output hB ----
    hipMemsetAsync(agg, 0, (size_t)N_NODES_C * 32 * sizeof(float), stream);
    {
        long long tot = (long long)N_EDGES_C * 8;
        int blocks = (int)((tot + 255) / 256);
        scatter_kernel<32><<<blocks, 256, 0, stream>>>(x, src, dst, agg, N_EDGES_C);
    }
    transform_kernel<32, 32><<<(N_NODES_C + 7) / 8, 256, 0, stream>>>(
        agg, x, w1_rel, b1, w1_root, hB, N_NODES_C);

    // ---- layer 2: d_in=32 -> d_out=64, input hB, output hC ----
    hipMemsetAsync(agg, 0, (size_t)N_NODES_C * 32 * sizeof(float), stream);
    {
        long long tot = (long long)N_EDGES_C * 8;
        int blocks = (int)((tot + 255) / 256);
        scatter_kernel<32><<<blocks, 256, 0, stream>>>(hB, src, dst, agg, N_EDGES_C);
    }
    transform_kernel<32, 64><<<(N_NODES_C + 3) / 4, 256, 0, stream>>>(
        agg, hB, w2_rel, b2, w2_root, hC, N_NODES_C);

    // ---- layer 3: d_in=64 -> d_out=64, input hC, output hB ----
    hipMemsetAsync(agg, 0, (size_t)N_NODES_C * 64 * sizeof(float), stream);
    {
        long long tot = (long long)N_EDGES_C * 16;
        int blocks = (int)((tot + 255) / 256);
        scatter_kernel<64><<<blocks, 256, 0, stream>>>(hC, src, dst, agg, N_EDGES_C);
    }
    transform_kernel<64, 64><<<(N_NODES_C + 3) / 4, 256, 0, stream>>>(
        agg, hC, w3_rel, b3, w3_root, hB, N_NODES_C);

    // ---- mean pool ----
    hipMemsetAsync(sums, 0, ((size_t)N_GRAPHS_C * 64 + N_GRAPHS_C) * sizeof(float), stream);
    pool_kernel<<<(N_NODES_C + POOL_CHUNK - 1) / POOL_CHUNK, 64, 0, stream>>>(
        hB, batch, sums, cnts, N_NODES_C);

    // ---- MLP head + log_softmax ----
    mlp_kernel<<<N_GRAPHS_C, 64, 0, stream>>>(
        sums, cnts, fw1, fb1, fw2, fb2, fw3, fb3, out);
}

// Round 2
// 634.899 us; speedup vs baseline: 4.7069x; 4.7069x over previous
//
#include <hip/hip_runtime.h>
#include <hip/hip_bf16.h>
#include <math.h>

#define N_NODES_C 100000
#define N_EDGES_C 1600000
#define N_GRAPHS_C 512
#define SCAN_CHUNK 1024   // elements per scan block
#define SCAN_NB ((N_NODES_C + SCAN_CHUNK) / SCAN_CHUNK + 1)  // generous

__device__ __forceinline__ float elu_f(float x) { return x > 0.f ? x : expm1f(x); }

__device__ __forceinline__ int wave_incl_scan(int v) {
    int lane = threadIdx.x & 63;
#pragma unroll
    for (int o = 1; o < 64; o <<= 1) {
        int t = __shfl_up(v, o);
        if (lane >= o) v += t;
    }
    return v;
}

__device__ __forceinline__ int wave_sum_i(int v) {
#pragma unroll
    for (int o = 32; o > 0; o >>= 1) v += __shfl_xor(v, o);
    return v;
}

// ---------------------------------------------------------------------------
// CSR build: histogram of in-degrees, exclusive scan, positioned fill.
// ---------------------------------------------------------------------------
__global__ __launch_bounds__(256) void hist_kernel(
    const int* __restrict__ dst, int* __restrict__ deg, int nE)
{
    int e = blockIdx.x * 256 + threadIdx.x;
    if (e < nE) atomicAdd(&deg[dst[e]], 1);
}

__global__ __launch_bounds__(256) void scan_pass1(
    const int* __restrict__ deg, int* __restrict__ bsum, int n)
{
    int base = blockIdx.x * SCAN_CHUNK;
    int s = 0;
    for (int i = threadIdx.x; i < SCAN_CHUNK; i += 256) {
        int idx = base + i;
        if (idx < n) s += deg[idx];
    }
    s = wave_sum_i(s);
    __shared__ int ws[4];
    int lane = threadIdx.x & 63, w = threadIdx.x >> 6;
    if (lane == 0) ws[w] = s;
    __syncthreads();
    if (threadIdx.x == 0) bsum[blockIdx.x] = ws[0] + ws[1] + ws[2] + ws[3];
}

__global__ __launch_bounds__(128) void scan_pass2(int* __restrict__ bsum, int nb)
{
    int tid = threadIdx.x;  // 128 threads, nb <= 128
    int v = tid < nb ? bsum[tid] : 0;
    int lane = tid & 63, w = tid >> 6;
    int incl = wave_incl_scan(v);
    __shared__ int ws[2];
    if (lane == 63) ws[w] = incl;
    __syncthreads();
    int off = (w == 1) ? ws[0] : 0;
    if (tid < nb) bsum[tid] = off + incl - v;  // exclusive
}

__global__ __launch_bounds__(256) void scan_pass3(
    const int* __restrict__ deg, const int* __restrict__ bsum,
    int* __restrict__ row_start, int* __restrict__ pos, int n)
{
    int base = blockIdx.x * SCAN_CHUNK + threadIdx.x * 4;
    int v[4];
#pragma unroll
    for (int k = 0; k < 4; ++k) {
        int idx = base + k;
        v[k] = (idx < n) ? deg[idx] : 0;
    }
    int lsum = v[0] + v[1] + v[2] + v[3];
    int incl = wave_incl_scan(lsum);
    __shared__ int ws[4];
    int lane = threadIdx.x & 63, w = threadIdx.x >> 6;
    if (lane == 63) ws[w] = incl;
    __syncthreads();
    int woff = 0;
    for (int i = 0; i < w; ++i) woff += ws[i];
    int p = bsum[blockIdx.x] + woff + incl - lsum;  // exclusive base
#pragma unroll
    for (int k = 0; k < 4; ++k) {
        int idx = base + k;
        if (idx <= n) row_start[idx] = p;
        if (idx < n)  pos[idx] = p;
        p += v[k];
    }
}

__global__ __launch_bounds__(256) void fill_kernel(
    const int* __restrict__ src, const int* __restrict__ dst,
    int* __restrict__ pos, int* __restrict__ ssrc, int nE)
{
    int e = blockIdx.x * 256 + threadIdx.x;
    if (e < nE) {
        int p = atomicAdd(&pos[dst[e]], 1);
        ssrc[p] = src[e];
    }
}

// ---------------------------------------------------------------------------
// Gather-sum aggregation: agg[n] = sum_{e in CSR[n]} x[ssrc[e]].
// D/4 lanes per node, float4 per lane, register accumulation, no atomics.
// ---------------------------------------------------------------------------
template<int D>
__global__ __launch_bounds__(256) void gather_agg(
    const float* __restrict__ x, const int* __restrict__ row_start,
    const int* __restrict__ ssrc, float* __restrict__ agg, int nNodes)
{
    const int L = D / 4;        // lanes per node
    const int NPB = 256 / L;    // nodes per block
    int local = threadIdx.x / L;
    int lane  = threadIdx.x % L;
    int n = blockIdx.x * NPB + local;
    if (n >= nNodes) return;
    int beg = row_start[n], end = row_start[n + 1];
    float4 acc = make_float4(0.f, 0.f, 0.f, 0.f);
    int e = beg;
    for (; e + 1 < end; e += 2) {
        int s0 = ssrc[e], s1 = ssrc[e + 1];
        float4 v0 = *reinterpret_cast<const float4*>(x + (size_t)s0 * D + lane * 4);
        float4 v1 = *reinterpret_cast<const float4*>(x + (size_t)s1 * D + lane * 4);
        acc.x += v0.x; acc.y += v0.y; acc.z += v0.z; acc.w += v0.w;
        acc.x += v1.x; acc.y += v1.y; acc.z += v1.z; acc.w += v1.w;
    }
    if (e < end) {
        int s0 = ssrc[e];
        float4 v0 = *reinterpret_cast<const float4*>(x + (size_t)s0 * D + lane * 4);
        acc.x += v0.x; acc.y += v0.y; acc.z += v0.z; acc.w += v0.w;
    }
    *reinterpret_cast<float4*>(agg + (size_t)n * D + lane * 4) = acc;
}

// ---------------------------------------------------------------------------
// Node transform: out[n][j] = ELU( agg[n]@w_rel + x[n]@w_root + b )[j]
// ---------------------------------------------------------------------------
template<int DIN, int DOUT>
__global__ __launch_bounds__(256) void transform_kernel(
    const float* __restrict__ agg, const float* __restrict__ xin,
    const float* __restrict__ w_rel, const float* __restrict__ bias,
    const float* __restrict__ w_root, float* __restrict__ out, int nNodes)
{
    __shared__ float wr[DIN * DOUT];
    __shared__ float wt[DIN * DOUT];
    for (int i = threadIdx.x; i < DIN * DOUT; i += 256) {
        wr[i] = w_rel[i];
        wt[i] = w_root[i];
    }
    __syncthreads();

    const int NPB = 256 / DOUT;
    int local = threadIdx.x / DOUT;
    int j = threadIdx.x % DOUT;
    int n = blockIdx.x * NPB + local;
    if (n >= nNodes) return;

    const float* ar = agg + (size_t)n * DIN;
    const float* xr = xin + (size_t)n * DIN;
    float acc = bias[j];
#pragma unroll
    for (int k = 0; k < DIN; ++k) {
        acc += ar[k] * wr[k * DOUT + j] + xr[k] * wt[k * DOUT + j];
    }
    out[(size_t)n * DOUT + j] = elu_f(acc);
}

// ---------------------------------------------------------------------------
// Mean-pool over sorted `batch`.
// ---------------------------------------------------------------------------
#define POOL_CHUNK 256
__global__ __launch_bounds__(64) void pool_kernel(
    const float* __restrict__ h, const int* __restrict__ batch,
    float* __restrict__ sums, float* __restrict__ cnts, int nNodes)
{
    int j = threadIdx.x;
    int start = blockIdx.x * POOL_CHUNK;
    int end = start + POOL_CHUNK;
    if (end > nNodes) end = nNodes;
    if (start >= end) return;

    int g = batch[start];
    float acc = 0.f;
    float c = 0.f;
    for (int n = start; n < end; ++n) {
        int gn = batch[n];
        if (gn != g) {
            unsafeAtomicAdd(&sums[(size_t)g * 64 + j], acc);
            if (j == 0) unsafeAtomicAdd(&cnts[g], c);
            acc = 0.f; c = 0.f; g = gn;
        }
        acc += h[(size_t)n * 64 + j];
        c += 1.f;
    }
    unsafeAtomicAdd(&sums[(size_t)g * 64 + j], acc);
    if (j == 0) unsafeAtomicAdd(&cnts[g], c);
}

// ---------------------------------------------------------------------------
// MLP head + log_softmax: one 64-thread block per graph.
// ---------------------------------------------------------------------------
__global__ __launch_bounds__(64) void mlp_kernel(
    const float* __restrict__ sums, const float* __restrict__ cnts,
    const float* __restrict__ fw1, const float* __restrict__ fb1,
    const float* __restrict__ fw2, const float* __restrict__ fb2,
    const float* __restrict__ fw3, const float* __restrict__ fb3,
    float* __restrict__ out)
{
    int g = blockIdx.x;
    int j = threadIdx.x;
    __shared__ float p[64];
    __shared__ float z1[64];
    __shared__ float z2[32];
    __shared__ float z3[10];
    __shared__ float lse;

    float c = fmaxf(cnts[g], 1.f);
    p[j] = sums[(size_t)g * 64 + j] / c;
    __syncthreads();

    float a = fb1[j];
#pragma unroll
    for (int k = 0; k < 64; ++k) a += p[k] * fw1[k * 64 + j];
    z1[j] = elu_f(a);
    __syncthreads();

    if (j < 32) {
        float a2 = fb2[j];
#pragma unroll
        for (int k = 0; k < 64; ++k) a2 += z1[k] * fw2[k * 32 + j];
        z2[j] = elu_f(a2);
    }
    __syncthreads();

    if (j < 10) {
        float a3 = fb3[j];
#pragma unroll
        for (int k = 0; k < 32; ++k) a3 += z2[k] * fw3[k * 10 + j];
        z3[j] = a3;
    }
    __syncthreads();

    if (j == 0) {
        float m = -1e30f;
        for (int i = 0; i < 10; ++i) m = fmaxf(m, z3[i]);
        float s = 0.f;
        for (int i = 0; i < 10; ++i) s += expf(z3[i] - m);
        lse = logf(s) + m;
    }
    __syncthreads();

    if (j < 10) out[(size_t)g * 10 + j] = z3[j] - lse;
}

// ---------------------------------------------------------------------------
extern "C" void kernel_launch(void* const* d_in, const int* in_sizes, int n_in,
                              void* d_out, int out_size, void* d_ws, size_t ws_size,
                              hipStream_t stream)
{
    const float* x       = (const float*)d_in[0];
    const int*   ei      = (const int*)  d_in[1];
    const int*   batch   = (const int*)  d_in[2];
    const float* w1_rel  = (const float*)d_in[3];
    const float* b1      = (const float*)d_in[4];
    const float* w1_root = (const float*)d_in[5];
    const float* w2_rel  = (const float*)d_in[6];
    const float* b2      = (const float*)d_in[7];
    const float* w2_root = (const float*)d_in[8];
    const float* w3_rel  = (const float*)d_in[9];
    const float* b3      = (const float*)d_in[10];
    const float* w3_root = (const float*)d_in[11];
    const float* fw1     = (const float*)d_in[12];
    const float* fb1     = (const float*)d_in[13];
    const float* fw2     = (const float*)d_in[14];
    const float* fb2     = (const float*)d_in[15];
    const float* fw3     = (const float*)d_in[16];
    const float* fb3     = (const float*)d_in[17];
    float* out = (float*)d_out;

    const int* src = ei;
    const int* dst = ei + N_EDGES_C;

    // workspace layout
    float* agg  = (float*)d_ws;                          // N*64 f
    float* hB   = agg  + (size_t)N_NODES_C * 64;         // N*64 f
    float* hC   = hB   + (size_t)N_NODES_C * 64;         // N*64 f
    float* sums = hC   + (size_t)N_NODES_C * 64;         // 512*64 f
    float* cnts = sums + (size_t)N_GRAPHS_C * 64;        // 512 f
    int*   deg  = (int*)(cnts + N_GRAPHS_C);             // N int
    int*   row_start = deg + N_NODES_C;                  // N+1 int
    int*   pos  = row_start + N_NODES_C + 1;             // N int
    int*   bsum = pos + N_NODES_C;                       // SCAN_NB int
    int*   ssrc = bsum + SCAN_NB;                        // nE int

    const int nb = (N_NODES_C + SCAN_CHUNK - 1) / SCAN_CHUNK;  // 98

    // ---- CSR build (once, reused by all 3 layers) ----
    hipMemsetAsync(deg, 0, (size_t)N_NODES_C * sizeof(int), stream);
    hist_kernel<<<(N_EDGES_C + 255) / 256, 256, 0, stream>>>(dst, deg, N_EDGES_C);
    scan_pass1<<<nb, 256, 0, stream>>>(deg, bsum, N_NODES_C);
    scan_pass2<<<1, 128, 0, stream>>>(bsum, nb);
    scan_pass3<<<nb, 256, 0, stream>>>(deg, bsum, row_start, pos, N_NODES_C);
    fill_kernel<<<(N_EDGES_C + 255) / 256, 256, 0, stream>>>(src, dst, pos, ssrc, N_EDGES_C);

    // ---- layer 1: 32 -> 32, input x, output hB ----
    gather_agg<32><<<(N_NODES_C + 31) / 32, 256, 0, stream>>>(x, row_start, ssrc, agg, N_NODES_C);
    transform_kernel<32, 32><<<(N_NODES_C + 7) / 8, 256, 0, stream>>>(
        agg, x, w1_rel, b1, w1_root, hB, N_NODES_C);

    // ---- layer 2: 32 -> 64, input hB, output hC ----
    gather_agg<32><<<(N_NODES_C + 31) / 32, 256, 0, stream>>>(hB, row_start, ssrc, agg, N_NODES_C);
    transform_kernel<32, 64><<<(N_NODES_C + 3) / 4, 256, 0, stream>>>(
        agg, hB, w2_rel, b2, w2_root, hC, N_NODES_C);

    // ---- layer 3: 64 -> 64, input hC, output hB ----
    gather_agg<64><<<(N_NODES_C + 15) / 16, 256, 0, stream>>>(hC, row_start, ssrc, agg, N_NODES_C);
    transform_kernel<64, 64><<<(N_NODES_C + 3) / 4, 256, 0, stream>>>(
        agg, hC, w3_rel, b3, w3_root, hB, N_NODES_C);

    // ---- mean pool ----
    hipMemsetAsync(sums, 0, ((size_t)N_GRAPHS_C * 64 + N_GRAPHS_C) * sizeof(float), stream);
    pool_kernel<<<(N_NODES_C + POOL_CHUNK - 1) / POOL_CHUNK, 64, 0, stream>>>(
        hB, batch, sums, cnts, N_NODES_C);

    // ---- MLP head + log_softmax ----
    mlp_kernel<<<N_GRAPHS_C, 64, 0, stream>>>(
        sums, cnts, fw1, fb1, fw2, fb2, fw3, fb3, out);
}